// Round 1
// 547.112 us; speedup vs baseline: 1.9507x; 1.9507x over previous
//
#include <hip/hip_runtime.h>
#include <math.h>

// max_valences table: {0:4,1:3,2:2,3:6,4:1,5:1,6:1,7:1,8:4,9:4,10:4}, default 4
__constant__ float c_maxv[11] = {4.f, 3.f, 2.f, 6.f, 1.f, 1.f, 1.f, 1.f, 4.f, 4.f, 4.f};

#define NREP 8        // fallback path: counter replicas
#define RSHIFT 11
#define RANGE 2048    // nodes per bucket (1 << RSHIFT)
#define EPB 8192      // edges per scatter block
#define BPAD 256      // padded bucket count (scan width / block size)

// ======================= NEW BINNED PATH =======================

// Phase 1: bin row indices into per-bucket segments.
// Per block: LDS histogram over buckets -> scan -> ONE global atomic per
// bucket (reservation) -> local counting-sort in LDS -> coalesced u16 writes.
// Converts 16M device-scope atomics into ~480K reservations + LDS atomics.
__global__ __launch_bounds__(256)
void scatter_kernel(const int* __restrict__ row, unsigned short* __restrict__ seg,
                    unsigned int* __restrict__ gcursor, int E, int CAP) {
    __shared__ unsigned int hist[BPAD];   // per-bucket count (this block)
    __shared__ unsigned int scn[BPAD];    // inclusive scan of hist
    __shared__ unsigned int place[BPAD];  // running placement cursor (exclusive ofs)
    __shared__ unsigned int gbase[BPAD];  // global reservation base per bucket
    __shared__ int sbuf[EPB];             // locally sorted values

    const int tid = threadIdx.x;
    const int base = blockIdx.x * EPB;
    const int nvalid = min(EPB, E - base);
    const bool full = (nvalid == EPB);

    hist[tid] = 0;
    __syncthreads();

    int vals[32];  // only statically indexed (avoid scratch)
    if (full) {
        #pragma unroll
        for (int k = 0; k < 8; ++k) {
            int4 r = reinterpret_cast<const int4*>(row + base)[k * 256 + tid];
            vals[4*k+0] = r.x; vals[4*k+1] = r.y; vals[4*k+2] = r.z; vals[4*k+3] = r.w;
        }
        #pragma unroll
        for (int k = 0; k < 32; ++k)
            atomicAdd(&hist[((unsigned)vals[k]) >> RSHIFT], 1u);
    } else {
        for (int i = tid; i < nvalid; i += 256)
            atomicAdd(&hist[((unsigned)row[base + i]) >> RSHIFT], 1u);
    }
    __syncthreads();

    const unsigned int mycnt = hist[tid];
    // global reservation: one atomic per bucket per block (latency overlaps scan)
    gbase[tid] = atomicAdd(&gcursor[tid], mycnt);
    scn[tid] = mycnt;
    __syncthreads();
    #pragma unroll
    for (int off = 1; off < BPAD; off <<= 1) {
        unsigned int v = (tid >= off) ? scn[tid - off] : 0u;
        __syncthreads();
        scn[tid] += v;
        __syncthreads();
    }
    place[tid] = scn[tid] - mycnt;  // exclusive offset
    __syncthreads();

    if (full) {
        #pragma unroll
        for (int k = 0; k < 32; ++k) {
            int v = vals[k];
            unsigned int p = atomicAdd(&place[((unsigned)v) >> RSHIFT], 1u);
            sbuf[p] = v;
        }
    } else {
        for (int i = tid; i < nvalid; i += 256) {
            int v = row[base + i];
            unsigned int p = atomicAdd(&place[((unsigned)v) >> RSHIFT], 1u);
            sbuf[p] = v;
        }
    }
    __syncthreads();

    // coalesced write-out: bucket-contiguous runs, u16 payload (low 11 bits)
    for (int i = tid; i < nvalid; i += 256) {
        int v = sbuf[i];
        int b = ((unsigned)v) >> RSHIFT;
        unsigned int ofs = scn[b] - hist[b];                  // exclusive local start
        unsigned int pos = gbase[b] + ((unsigned)i - ofs);    // slot in bucket segment
        if (pos < (unsigned)CAP)                              // defensive (cannot trigger statistically)
            seg[(size_t)b * (size_t)CAP + pos] = (unsigned short)(v & (RANGE - 1));
    }
}

// Phase 2: one block owns one bucket exclusively. LDS histogram (no coherence
// traffic), then fused node epilogue: valence lookup, violation, sarr, viol.
__global__ __launch_bounds__(256)
void bucket_kernel(const unsigned short* __restrict__ seg,
                   const unsigned int* __restrict__ gcursor,
                   const int* __restrict__ atom_types,
                   float* __restrict__ sarr, float* __restrict__ viol,
                   int N, int CAP, float inv_n) {
    __shared__ unsigned int h2[RANGE];   // 8 KB
    const int tid = threadIdx.x;
    const int b = blockIdx.x;

    #pragma unroll
    for (int j = 0; j < RANGE / 256; ++j) h2[tid + j * 256] = 0;
    __syncthreads();

    unsigned int cnt = gcursor[b];
    if (cnt > (unsigned)CAP) cnt = (unsigned)CAP;
    const unsigned short* s = seg + (size_t)b * (size_t)CAP;

    // vectorized reads: uint2 = 4 ushorts (segment base is 8B-aligned: CAP % 64 == 0)
    const uint2* s4 = (const uint2*)s;
    unsigned int n4 = cnt >> 2;
    for (unsigned int i = tid; i < n4; i += 256) {
        uint2 w = s4[i];
        atomicAdd(&h2[w.x & 0xffffu], 1u);
        atomicAdd(&h2[w.x >> 16], 1u);
        atomicAdd(&h2[w.y & 0xffffu], 1u);
        atomicAdd(&h2[w.y >> 16], 1u);
    }
    for (unsigned int i = (n4 << 2) + tid; i < cnt; i += 256)
        atomicAdd(&h2[s[i]], 1u);
    __syncthreads();

    float local = 0.0f;
    const int rbase = b << RSHIFT;
    #pragma unroll
    for (int j = 0; j < RANGE / 256; ++j) {
        int idx = tid + j * 256;
        int r = rbase + idx;
        if (r < N) {
            float c = (float)h2[idx];
            int t = atom_types[r];
            float maxv = ((unsigned)t < 11u) ? c_maxv[t] : 4.0f;
            float v = fmaxf(c - maxv, 0.0f);
            sarr[r] = 1.0f - 0.1f * v;
            local += v * v;
        }
    }
    for (int off = 32; off > 0; off >>= 1)
        local += __shfl_down(local, off, 64);
    __shared__ float sred[4];
    if ((tid & 63) == 0) sred[tid >> 6] = local;
    __syncthreads();
    if (tid == 0)
        atomicAdd(viol, (sred[0] + sred[1] + sred[2] + sred[3]) * inv_n);
}

// ======================= FALLBACK PATH (previous verified kernels) =======================

__global__ __launch_bounds__(256) void count_kernel(const int* __restrict__ row,
                                                    unsigned int* __restrict__ counts,
                                                    int nvec, int E, int N) {
    unsigned int* my = counts + (size_t)(blockIdx.x & (NREP - 1)) * (size_t)N;
    int i = blockIdx.x * 256 + threadIdx.x;
    if (i < nvec) {
        int4 r = reinterpret_cast<const int4*>(row)[i];
        atomicAdd(&my[r.x], 1u);
        atomicAdd(&my[r.y], 1u);
        atomicAdd(&my[r.z], 1u);
        atomicAdd(&my[r.w], 1u);
    }
    int e = nvec * 4 + i;
    if (e < E) atomicAdd(&my[row[e]], 1u);
}

__global__ __launch_bounds__(256) void node_kernel(const unsigned int* __restrict__ counts,
                                                   const int* __restrict__ atom_types,
                                                   float* __restrict__ sarr,
                                                   float* __restrict__ viol,
                                                   int N, float inv_n) {
    int stride = gridDim.x * 256;
    float local = 0.0f;
    for (int r = blockIdx.x * 256 + threadIdx.x; r < N; r += stride) {
        unsigned int c = 0;
        #pragma unroll
        for (int k = 0; k < NREP; ++k) c += counts[(size_t)k * (size_t)N + r];
        int t = atom_types[r];
        float maxv = (t >= 0 && t < 11) ? c_maxv[t] : 4.0f;
        float v = fmaxf((float)c - maxv, 0.0f);
        sarr[r] = 1.0f - 0.1f * v;
        local += v * v;
    }
    for (int off = 32; off > 0; off >>= 1)
        local += __shfl_down(local, off, 64);
    __shared__ float sdata[4];
    if ((threadIdx.x & 63) == 0) sdata[threadIdx.x >> 6] = local;
    __syncthreads();
    if (threadIdx.x == 0)
        atomicAdd(viol, (sdata[0] + sdata[1] + sdata[2] + sdata[3]) * inv_n);
}

// ======================= SCALE (unchanged) =======================

__global__ __launch_bounds__(256) void scale_kernel(const float4* __restrict__ h,
                                                    const float* __restrict__ sarr,
                                                    float4* __restrict__ out,
                                                    int total, int cpr_shift) {
    int stride = gridDim.x * 256;
    for (int idx = blockIdx.x * 256 + threadIdx.x; idx < total; idx += stride) {
        float s = sarr[idx >> cpr_shift];
        float4 hv = h[idx];
        hv.x *= s; hv.y *= s; hv.z *= s; hv.w *= s;
        out[idx] = hv;
    }
}

extern "C" void kernel_launch(void* const* d_in, const int* in_sizes, int n_in,
                              void* d_out, int out_size, void* d_ws, size_t ws_size,
                              hipStream_t stream) {
    const float* h          = (const float*)d_in[0];
    const int*   edge       = (const int*)d_in[1];   // row = edge[0..E-1]
    const int*   atom_types = (const int*)d_in[3];

    int N = in_sizes[3];
    int D = in_sizes[0] / N;        // 128
    int E = in_sizes[1] / 2;        // 16M

    float* out  = (float*)d_out;
    float* viol = out + (size_t)N * (size_t)D;
    hipMemsetAsync(viol, 0, sizeof(float), stream);

    int B = (N + RANGE - 1) >> RSHIFT;   // 245 buckets for N=500000

    // per-bucket capacity: mean + 16 sigma + 1024, rounded to 64 (overflow P ~ e^-128)
    double mean = (double)E * (double)RANGE / (double)N;
    int CAP = (int)(mean + 16.0 * sqrt(mean > 1.0 ? mean : 1.0) + 1024.0);
    CAP = (CAP + 63) & ~63;

    size_t seg_bytes = ((size_t)B * (size_t)CAP * 2 + 255) & ~(size_t)255;
    size_t need_new  = seg_bytes + 1024 + (size_t)N * 4;

    float* sarr;
    if (B <= BPAD && ws_size >= need_new) {
        // ws layout: [seg u16 (B*CAP)][gcursor 256 u32][sarr N f32]
        unsigned short* seg     = (unsigned short*)d_ws;
        unsigned int*   gcursor = (unsigned int*)((char*)d_ws + seg_bytes);
        sarr = (float*)((char*)d_ws + seg_bytes + 1024);

        hipMemsetAsync(gcursor, 0, BPAD * sizeof(unsigned int), stream);

        int sblocks = (E + EPB - 1) / EPB;
        scatter_kernel<<<sblocks, 256, 0, stream>>>(edge, seg, gcursor, E, CAP);
        bucket_kernel<<<B, 256, 0, stream>>>(seg, gcursor, atom_types, sarr, viol,
                                             N, CAP, 1.0f / (float)N);
    } else {
        // fallback: previous verified path
        unsigned int* counts = (unsigned int*)d_ws;
        sarr = (float*)((char*)d_ws + (size_t)NREP * N * 4);
        hipMemsetAsync(counts, 0, (size_t)NREP * N * sizeof(unsigned int), stream);
        int nvec = E / 4;
        int cblocks = (nvec + 255) / 256;
        count_kernel<<<cblocks, 256, 0, stream>>>(edge, counts, nvec, E, N);
        node_kernel<<<512, 256, 0, stream>>>(counts, atom_types, sarr, viol, N,
                                             1.0f / (float)N);
    }

    int cpr = D / 4;
    int cpr_shift = 0; while ((1 << cpr_shift) < cpr) ++cpr_shift;
    int total = N * cpr;
    scale_kernel<<<8192, 256, 0, stream>>>((const float4*)h, sarr,
                                           (float4*)out, total, cpr_shift);
}

// Round 3
// 535.611 us; speedup vs baseline: 1.9926x; 1.0215x over previous
//
#include <hip/hip_runtime.h>
#include <math.h>

// max_valences table: {0:4,1:3,2:2,3:6,4:1,5:1,6:1,7:1,8:4,9:4,10:4}, default 4
__constant__ float c_maxv[11] = {4.f, 3.f, 2.f, 6.f, 1.f, 1.f, 1.f, 1.f, 4.f, 4.f, 4.f};

#define NREP 8        // fallback path: counter replicas
#define RSHIFT 11
#define RANGE 2048    // nodes per bucket (1 << RSHIFT)
#define EPB 8192      // edges per scatter block
#define BPAD 256      // padded bucket count (scan width / block size)

// clang ext_vector types: required by __builtin_nontemporal_load/store
// (HIP_vector_type float4/int4 are rejected by the builtin).
typedef float f4 __attribute__((ext_vector_type(4)));
typedef int   i4 __attribute__((ext_vector_type(4)));

// ======================= BINNED PATH =======================

// Phase 1: bin row indices into per-bucket segments.
// Per block: LDS histogram over buckets -> shfl scan (1 barrier) -> ONE global
// atomic per bucket (reservation) -> local counting-sort in LDS -> coalesced
// u16 writes. 16M device atomics become ~480K reservations + LDS atomics.
__global__ __launch_bounds__(256)
void scatter_kernel(const int* __restrict__ row, unsigned short* __restrict__ seg,
                    unsigned int* __restrict__ gcursor, int E, int CAP) {
    __shared__ unsigned int hist[BPAD];   // per-bucket count; later: run starts
    __shared__ unsigned int scn[BPAD];    // inclusive scan of hist
    __shared__ unsigned int place[BPAD];  // running placement cursor
    __shared__ unsigned int gbase[BPAD];  // global reservation base per bucket
    __shared__ unsigned int wtot[4];      // per-wave scan totals
    __shared__ int sbuf[EPB];             // locally sorted values

    const int tid = threadIdx.x;
    const int base = blockIdx.x * EPB;
    const int nvalid = min(EPB, E - base);
    const bool full = (nvalid == EPB);

    hist[tid] = 0;
    __syncthreads();

    int vals[32];  // only statically indexed (avoid scratch)
    if (full) {
        #pragma unroll
        for (int k = 0; k < 8; ++k) {
            i4 r = __builtin_nontemporal_load(
                reinterpret_cast<const i4*>(row + base) + k * 256 + tid);
            vals[4*k+0] = r.x; vals[4*k+1] = r.y; vals[4*k+2] = r.z; vals[4*k+3] = r.w;
        }
        #pragma unroll
        for (int k = 0; k < 32; ++k)
            atomicAdd(&hist[((unsigned)vals[k]) >> RSHIFT], 1u);
    } else {
        for (int i = tid; i < nvalid; i += 256)
            atomicAdd(&hist[((unsigned)row[base + i]) >> RSHIFT], 1u);
    }
    __syncthreads();

    const unsigned int mycnt = hist[tid];
    // global reservation: latency overlaps the scan below
    gbase[tid] = atomicAdd(&gcursor[tid], mycnt);

    // wave-level inclusive scan (no barriers inside), then cross-wave offset
    unsigned int v = mycnt;
    #pragma unroll
    for (int off = 1; off < 64; off <<= 1) {
        unsigned int n = __shfl_up(v, off, 64);
        if ((tid & 63) >= off) v += n;
    }
    if ((tid & 63) == 63) wtot[tid >> 6] = v;
    __syncthreads();
    unsigned int wofs = 0;
    #pragma unroll
    for (int w = 0; w < 4; ++w) wofs += (w < (tid >> 6)) ? wtot[w] : 0u;
    unsigned int inc = v + wofs;          // inclusive scan value
    scn[tid] = inc;
    place[tid] = inc - mycnt;             // exclusive offset
    __syncthreads();

    if (full) {
        #pragma unroll
        for (int k = 0; k < 32; ++k) {
            int x = vals[k];
            unsigned int p = atomicAdd(&place[((unsigned)x) >> RSHIFT], 1u);
            sbuf[p] = x;
        }
    } else {
        for (int i = tid; i < nvalid; i += 256) {
            int x = row[base + i];
            unsigned int p = atomicAdd(&place[((unsigned)x) >> RSHIFT], 1u);
            sbuf[p] = x;
        }
    }
    __syncthreads();
    hist[tid] = scn[tid] - hist[tid];     // per-bucket local run start
    __syncthreads();

    // coalesced write-out: bucket-contiguous runs, u16 payload (low 11 bits)
    for (int i = tid; i < nvalid; i += 256) {
        int x = sbuf[i];
        int b = ((unsigned)x) >> RSHIFT;
        unsigned int pos = gbase[b] + ((unsigned)i - hist[b]);
        if (pos < (unsigned)CAP)          // defensive (cannot trigger statistically)
            seg[(size_t)b * (size_t)CAP + pos] = (unsigned short)(x & (RANGE - 1));
    }
}

// Phase 2 (fused): one 1024-thread block owns one bucket. LDS histogram of its
// segment, per-node valence epilogue into LDS svals, then stream the bucket's
// 2 MB slab of h -> out scaled by svals. viol via last-block ticket (no memset).
__global__ __launch_bounds__(1024)
void fused_kernel(const unsigned short* __restrict__ seg,
                  const unsigned int* __restrict__ gcursor,
                  const int* __restrict__ atom_types,
                  const float* __restrict__ h, float* __restrict__ out,
                  float* __restrict__ viol_out, float* __restrict__ vz,
                  unsigned int* __restrict__ done,
                  int N, int CAP, float inv_n, int nblocks) {
    __shared__ unsigned int h2[RANGE];    // 8 KB counters
    __shared__ float svals[RANGE];        // 8 KB per-node scale
    __shared__ float sred[16];

    const int tid = threadIdx.x;
    const int b = blockIdx.x;

    h2[tid] = 0; h2[tid + 1024] = 0;
    __syncthreads();

    unsigned int cnt = gcursor[b];
    if (cnt > (unsigned)CAP) cnt = (unsigned)CAP;
    const unsigned short* s = seg + (size_t)b * (size_t)CAP;

    // vectorized reads: uint2 = 4 ushorts (CAP % 64 == 0 -> 8B-aligned base)
    const uint2* s4 = (const uint2*)s;
    unsigned int n4 = cnt >> 2;
    for (unsigned int i = tid; i < n4; i += 1024) {
        uint2 w = s4[i];
        atomicAdd(&h2[w.x & 0xffffu], 1u);
        atomicAdd(&h2[w.x >> 16], 1u);
        atomicAdd(&h2[w.y & 0xffffu], 1u);
        atomicAdd(&h2[w.y >> 16], 1u);
    }
    for (unsigned int i = (n4 << 2) + tid; i < cnt; i += 1024)
        atomicAdd(&h2[s[i]], 1u);
    __syncthreads();

    // per-node epilogue into LDS
    const int rbase = b << RSHIFT;
    const int nr = min(RANGE, N - rbase);
    float local = 0.0f;
    #pragma unroll
    for (int j = 0; j < 2; ++j) {
        int idx = tid + j * 1024;
        int r = rbase + idx;
        if (r < N) {
            float c = (float)h2[idx];
            int t = atom_types[r];
            float maxv = ((unsigned)t < 11u) ? c_maxv[t] : 4.0f;
            float vv = fmaxf(c - maxv, 0.0f);
            svals[idx] = 1.0f - 0.1f * vv;
            local += vv * vv;
        }
    }
    __syncthreads();   // svals visible to all waves before streaming

    // stream h -> out for this bucket's rows (nt: never re-read)
    const f4* h4 = reinterpret_cast<const f4*>(h);
    f4* o4 = reinterpret_cast<f4*>(out);
    const size_t g4 = (size_t)rbase * 32;  // float4 index of slab start
    const int t4 = nr * 32;
    int i = tid;
    for (; i + 1024 < t4; i += 2048) {
        f4 a = __builtin_nontemporal_load(h4 + g4 + i);
        f4 c = __builtin_nontemporal_load(h4 + g4 + i + 1024);
        float sa = svals[i >> 5];
        float sc = svals[(i + 1024) >> 5];
        a *= sa;
        c *= sc;
        __builtin_nontemporal_store(a, o4 + g4 + i);
        __builtin_nontemporal_store(c, o4 + g4 + i + 1024);
    }
    for (; i < t4; i += 1024) {
        f4 a = __builtin_nontemporal_load(h4 + g4 + i);
        float sa = svals[i >> 5];
        a *= sa;
        __builtin_nontemporal_store(a, o4 + g4 + i);
    }

    // violation reduce + last-block ticket writes the scalar output
    for (int off = 32; off > 0; off >>= 1)
        local += __shfl_down(local, off, 64);
    if ((tid & 63) == 0) sred[tid >> 6] = local;
    __syncthreads();
    if (tid == 0) {
        float ssum = 0.0f;
        #pragma unroll
        for (int k = 0; k < 16; ++k) ssum += sred[k];
        atomicAdd(vz, ssum * inv_n);
        __threadfence();
        unsigned int t = atomicAdd(done, 1u);
        if (t == (unsigned)(nblocks - 1))
            *viol_out = atomicAdd(vz, 0.0f);   // RMW read at coherence point
    }
}

// ======================= FALLBACK PATH (previous verified kernels) =======================

__global__ __launch_bounds__(256) void count_kernel(const int* __restrict__ row,
                                                    unsigned int* __restrict__ counts,
                                                    int nvec, int E, int N) {
    unsigned int* my = counts + (size_t)(blockIdx.x & (NREP - 1)) * (size_t)N;
    int i = blockIdx.x * 256 + threadIdx.x;
    if (i < nvec) {
        int4 r = reinterpret_cast<const int4*>(row)[i];
        atomicAdd(&my[r.x], 1u);
        atomicAdd(&my[r.y], 1u);
        atomicAdd(&my[r.z], 1u);
        atomicAdd(&my[r.w], 1u);
    }
    int e = nvec * 4 + i;
    if (e < E) atomicAdd(&my[row[e]], 1u);
}

__global__ __launch_bounds__(256) void node_kernel(const unsigned int* __restrict__ counts,
                                                   const int* __restrict__ atom_types,
                                                   float* __restrict__ sarr,
                                                   float* __restrict__ viol,
                                                   int N, float inv_n) {
    int stride = gridDim.x * 256;
    float local = 0.0f;
    for (int r = blockIdx.x * 256 + threadIdx.x; r < N; r += stride) {
        unsigned int c = 0;
        #pragma unroll
        for (int k = 0; k < NREP; ++k) c += counts[(size_t)k * (size_t)N + r];
        int t = atom_types[r];
        float maxv = (t >= 0 && t < 11) ? c_maxv[t] : 4.0f;
        float v = fmaxf((float)c - maxv, 0.0f);
        sarr[r] = 1.0f - 0.1f * v;
        local += v * v;
    }
    for (int off = 32; off > 0; off >>= 1)
        local += __shfl_down(local, off, 64);
    __shared__ float sdata[4];
    if ((threadIdx.x & 63) == 0) sdata[threadIdx.x >> 6] = local;
    __syncthreads();
    if (threadIdx.x == 0)
        atomicAdd(viol, (sdata[0] + sdata[1] + sdata[2] + sdata[3]) * inv_n);
}

__global__ __launch_bounds__(256) void scale_kernel(const float4* __restrict__ h,
                                                    const float* __restrict__ sarr,
                                                    float4* __restrict__ out,
                                                    int total, int cpr_shift) {
    int stride = gridDim.x * 256;
    for (int idx = blockIdx.x * 256 + threadIdx.x; idx < total; idx += stride) {
        float s = sarr[idx >> cpr_shift];
        float4 hv = h[idx];
        hv.x *= s; hv.y *= s; hv.z *= s; hv.w *= s;
        out[idx] = hv;
    }
}

extern "C" void kernel_launch(void* const* d_in, const int* in_sizes, int n_in,
                              void* d_out, int out_size, void* d_ws, size_t ws_size,
                              hipStream_t stream) {
    const float* h          = (const float*)d_in[0];
    const int*   edge       = (const int*)d_in[1];   // row = edge[0..E-1]
    const int*   atom_types = (const int*)d_in[3];

    int N = in_sizes[3];
    int D = in_sizes[0] / N;        // 128
    int E = in_sizes[1] / 2;        // 16M

    float* out  = (float*)d_out;
    float* viol = out + (size_t)N * (size_t)D;

    int B = (N + RANGE - 1) >> RSHIFT;   // 245 buckets for N=500000

    // per-bucket capacity: mean + 16 sigma + 1024, rounded to 64 (overflow P ~ e^-128)
    double mean = (double)E * (double)RANGE / (double)N;
    int CAP = (int)(mean + 16.0 * sqrt(mean > 1.0 ? mean : 1.0) + 1024.0);
    CAP = (CAP + 63) & ~63;

    size_t seg_bytes = ((size_t)B * (size_t)CAP * 2 + 255) & ~(size_t)255;
    size_t ctl_bytes = (size_t)BPAD * 4 + 64;   // gcursor + vz + done
    size_t need_new  = seg_bytes + ctl_bytes;

    if (B <= BPAD && D == 128 && ws_size >= need_new) {
        // ws layout: [seg u16 (B*CAP)][gcursor BPAD u32][vz f32][done u32]
        unsigned short* seg     = (unsigned short*)d_ws;
        unsigned int*   gcursor = (unsigned int*)((char*)d_ws + seg_bytes);
        float*          vz      = (float*)((char*)d_ws + seg_bytes + (size_t)BPAD * 4);
        unsigned int*   done    = (unsigned int*)(vz + 1);

        (void)hipMemsetAsync(gcursor, 0, ctl_bytes, stream);  // cursors+vz+done

        int sblocks = (E + EPB - 1) / EPB;
        scatter_kernel<<<sblocks, 256, 0, stream>>>(edge, seg, gcursor, E, CAP);
        fused_kernel<<<B, 1024, 0, stream>>>(seg, gcursor, atom_types,
                                             h, out, viol, vz, done, N, CAP,
                                             1.0f / (float)N, B);
    } else {
        // fallback: previous verified path
        unsigned int* counts = (unsigned int*)d_ws;
        float* sarr = (float*)((char*)d_ws + (size_t)NREP * N * 4);
        (void)hipMemsetAsync(counts, 0, (size_t)NREP * N * sizeof(unsigned int), stream);
        (void)hipMemsetAsync(viol, 0, sizeof(float), stream);
        int nvec = E / 4;
        int cblocks = (nvec + 255) / 256;
        count_kernel<<<cblocks, 256, 0, stream>>>(edge, counts, nvec, E, N);
        node_kernel<<<512, 256, 0, stream>>>(counts, atom_types, sarr, viol, N,
                                             1.0f / (float)N);
        int cpr = D / 4;
        int cpr_shift = 0; while ((1 << cpr_shift) < cpr) ++cpr_shift;
        int total = N * cpr;
        scale_kernel<<<8192, 256, 0, stream>>>((const float4*)h, sarr,
                                               (float4*)out, total, cpr_shift);
    }
}

// Round 5
// 530.041 us; speedup vs baseline: 2.0135x; 1.0105x over previous
//
#include <hip/hip_runtime.h>
#include <math.h>

// max_valences table: {0:4,1:3,2:2,3:6,4:1,5:1,6:1,7:1,8:4,9:4,10:4}, default 4
__constant__ float c_maxv[11] = {4.f, 3.f, 2.f, 6.f, 1.f, 1.f, 1.f, 1.f, 4.f, 4.f, 4.f};

#define NREP 8        // fallback path: counter replicas
#define RSHIFT 11
#define RANGE 2048    // nodes per bucket (1 << RSHIFT)
#define EPB 8192      // edges per scatter block
#define SBLK 512      // scatter block threads (4 blocks/CU -> 2048 thr/CU, full occ)
#define BPAD 256      // padded bucket count (scan width)

// clang ext_vector types: required by __builtin_nontemporal_load/store
typedef float f4 __attribute__((ext_vector_type(4)));
typedef int   i4 __attribute__((ext_vector_type(4)));

// ======================= BINNED PATH =======================

// Phase 1: bin row indices into per-bucket segments.
// Per block: 4-way replicated LDS histogram (per 2-wave group) -> shfl scan ->
// ONE global atomic per bucket (reservation) -> counting-sort into per-group
// sub-ranges (replicated cursors, 4x less same-address serialization) ->
// coalesced u16 writes of bucket-contiguous runs.
__global__ __launch_bounds__(SBLK)
void scatter_kernel(const int* __restrict__ row, unsigned short* __restrict__ seg,
                    unsigned int* __restrict__ gcursor, int E, int CAP) {
    __shared__ unsigned int hist4[4][BPAD]; // per-group counts; later: group cursors
    __shared__ unsigned int scn[BPAD];      // per-bucket local run start (excl scan)
    __shared__ unsigned int gbase[BPAD];    // global reservation base per bucket
    __shared__ unsigned int wtot[4];        // per-wave scan totals
    __shared__ int sbuf[EPB];               // locally sorted values (32 KB)

    const int tid = threadIdx.x;
    const int grp = tid >> 7;               // 2-wave group: 0..3
    const int base = blockIdx.x * EPB;
    const int nvalid = min(EPB, E - base);
    const bool full = (nvalid == EPB);

    // full strided init of all 4*BPAD replica counters (round-4 bug: half-covered)
    #pragma unroll
    for (int j = 0; j < 4 * BPAD; j += SBLK)
        (&hist4[0][0])[j + tid] = 0;
    __syncthreads();

    int vals[16];  // only statically indexed (avoid scratch)
    if (full) {
        #pragma unroll
        for (int k = 0; k < 4; ++k) {
            i4 r = __builtin_nontemporal_load(
                reinterpret_cast<const i4*>(row + base) + k * SBLK + tid);
            vals[4*k+0] = r.x; vals[4*k+1] = r.y; vals[4*k+2] = r.z; vals[4*k+3] = r.w;
        }
        #pragma unroll
        for (int k = 0; k < 16; ++k)
            atomicAdd(&hist4[grp][((unsigned)vals[k]) >> RSHIFT], 1u);
    } else {
        for (int i = tid; i < nvalid; i += SBLK)
            atomicAdd(&hist4[grp][((unsigned)row[base + i]) >> RSHIFT], 1u);
    }
    __syncthreads();

    // threads 0..255: per-bucket totals, reservation, block-level exclusive scan
    unsigned int c0 = 0, c1 = 0, c2 = 0, tot = 0, v = 0;
    if (tid < BPAD) {
        c0 = hist4[0][tid]; c1 = hist4[1][tid]; c2 = hist4[2][tid];
        tot = c0 + c1 + c2 + hist4[3][tid];
        // global reservation: latency overlaps the scan below
        gbase[tid] = atomicAdd(&gcursor[tid], tot);
        v = tot;
        #pragma unroll
        for (int off = 1; off < 64; off <<= 1) {
            unsigned int n = __shfl_up(v, off, 64);
            if ((tid & 63) >= off) v += n;
        }
        if ((tid & 63) == 63) wtot[tid >> 6] = v;
    }
    __syncthreads();
    if (tid < BPAD) {
        unsigned int wofs = 0;
        #pragma unroll
        for (int w = 0; w < 4; ++w) wofs += (w < (tid >> 6)) ? wtot[w] : 0u;
        unsigned int excl = v + wofs - tot;     // exclusive scan value
        scn[tid] = excl;                        // bucket run start in sbuf
        hist4[0][tid] = excl;                   // group sub-range cursors
        hist4[1][tid] = excl + c0;
        hist4[2][tid] = excl + c0 + c1;
        hist4[3][tid] = excl + c0 + c1 + c2;
    }
    __syncthreads();

    if (full) {
        #pragma unroll
        for (int k = 0; k < 16; ++k) {
            int x = vals[k];
            unsigned int p = atomicAdd(&hist4[grp][((unsigned)x) >> RSHIFT], 1u);
            sbuf[p & (EPB - 1)] = x;    // mask: accounting bug => wrong answer, not fault
        }
    } else {
        for (int i = tid; i < nvalid; i += SBLK) {
            int x = row[base + i];
            unsigned int p = atomicAdd(&hist4[grp][((unsigned)x) >> RSHIFT], 1u);
            sbuf[p & (EPB - 1)] = x;
        }
    }
    __syncthreads();

    // coalesced write-out: bucket-contiguous runs, u16 payload (low 11 bits)
    for (int i = tid; i < nvalid; i += SBLK) {
        int x = sbuf[i];
        int b = ((unsigned)x) >> RSHIFT;
        unsigned int pos = gbase[b] + ((unsigned)i - scn[b]);
        if (pos < (unsigned)CAP)          // defensive (cannot trigger statistically)
            seg[(size_t)b * (size_t)CAP + pos] = (unsigned short)(x & (RANGE - 1));
    }
}

// Phase 2 (fused): one 1024-thread block owns one bucket. 4-way replicated LDS
// histogram of its segment (per 4-wave group), per-node valence epilogue into
// LDS svals, then stream the bucket's 2 MB slab of h -> out scaled by svals.
// viol via last-block ticket (no output memset).
__global__ __launch_bounds__(1024)
void fused_kernel(const unsigned short* __restrict__ seg,
                  const unsigned int* __restrict__ gcursor,
                  const int* __restrict__ atom_types,
                  const float* __restrict__ h, float* __restrict__ out,
                  float* __restrict__ viol_out, float* __restrict__ vz,
                  unsigned int* __restrict__ done,
                  int N, int CAP, float inv_n, int nblocks) {
    __shared__ unsigned int h2r[4][RANGE];  // 32 KB replicated counters
    __shared__ float svals[RANGE];          // 8 KB per-node scale
    __shared__ float sred[16];

    const int tid = threadIdx.x;
    const int g = tid >> 8;                 // 4-wave group: 0..3
    const int b = blockIdx.x;

    #pragma unroll
    for (int j = 0; j < 8; ++j) h2r[j >> 1][(j & 1) * 1024 + tid] = 0;
    __syncthreads();

    unsigned int cnt = gcursor[b];
    if (cnt > (unsigned)CAP) cnt = (unsigned)CAP;
    const unsigned short* s = seg + (size_t)b * (size_t)CAP;

    // vectorized reads: uint2 = 4 ushorts (CAP % 64 == 0 -> 8B-aligned base)
    const uint2* s4 = (const uint2*)s;
    unsigned int n4 = cnt >> 2;
    for (unsigned int i = tid; i < n4; i += 1024) {
        uint2 w = s4[i];
        atomicAdd(&h2r[g][w.x & 0xffffu], 1u);
        atomicAdd(&h2r[g][w.x >> 16], 1u);
        atomicAdd(&h2r[g][w.y & 0xffffu], 1u);
        atomicAdd(&h2r[g][w.y >> 16], 1u);
    }
    for (unsigned int i = (n4 << 2) + tid; i < cnt; i += 1024)
        atomicAdd(&h2r[g][s[i]], 1u);
    __syncthreads();

    // per-node epilogue into LDS
    const int rbase = b << RSHIFT;
    const int nr = min(RANGE, N - rbase);
    float local = 0.0f;
    #pragma unroll
    for (int j = 0; j < 2; ++j) {
        int idx = tid + j * 1024;
        int r = rbase + idx;
        if (r < N) {
            float c = (float)(h2r[0][idx] + h2r[1][idx] + h2r[2][idx] + h2r[3][idx]);
            int t = atom_types[r];
            float maxv = ((unsigned)t < 11u) ? c_maxv[t] : 4.0f;
            float vv = fmaxf(c - maxv, 0.0f);
            svals[idx] = 1.0f - 0.1f * vv;
            local += vv * vv;
        }
    }
    __syncthreads();   // svals visible to all waves before streaming

    // stream h -> out for this bucket's rows (nt: never re-read)
    const f4* h4 = reinterpret_cast<const f4*>(h);
    f4* o4 = reinterpret_cast<f4*>(out);
    const size_t g4 = (size_t)rbase * 32;  // float4 index of slab start
    const int t4 = nr * 32;
    int i = tid;
    for (; i + 1024 < t4; i += 2048) {
        f4 a = __builtin_nontemporal_load(h4 + g4 + i);
        f4 c = __builtin_nontemporal_load(h4 + g4 + i + 1024);
        float sa = svals[i >> 5];
        float sc = svals[(i + 1024) >> 5];
        a *= sa;
        c *= sc;
        __builtin_nontemporal_store(a, o4 + g4 + i);
        __builtin_nontemporal_store(c, o4 + g4 + i + 1024);
    }
    for (; i < t4; i += 1024) {
        f4 a = __builtin_nontemporal_load(h4 + g4 + i);
        float sa = svals[i >> 5];
        a *= sa;
        __builtin_nontemporal_store(a, o4 + g4 + i);
    }

    // violation reduce + last-block ticket writes the scalar output
    for (int off = 32; off > 0; off >>= 1)
        local += __shfl_down(local, off, 64);
    if ((tid & 63) == 0) sred[tid >> 6] = local;
    __syncthreads();
    if (tid == 0) {
        float ssum = 0.0f;
        #pragma unroll
        for (int k = 0; k < 16; ++k) ssum += sred[k];
        atomicAdd(vz, ssum * inv_n);
        __threadfence();
        unsigned int t = atomicAdd(done, 1u);
        if (t == (unsigned)(nblocks - 1))
            *viol_out = atomicAdd(vz, 0.0f);   // RMW read at coherence point
    }
}

// ======================= FALLBACK PATH (previous verified kernels) =======================

__global__ __launch_bounds__(256) void count_kernel(const int* __restrict__ row,
                                                    unsigned int* __restrict__ counts,
                                                    int nvec, int E, int N) {
    unsigned int* my = counts + (size_t)(blockIdx.x & (NREP - 1)) * (size_t)N;
    int i = blockIdx.x * 256 + threadIdx.x;
    if (i < nvec) {
        int4 r = reinterpret_cast<const int4*>(row)[i];
        atomicAdd(&my[r.x], 1u);
        atomicAdd(&my[r.y], 1u);
        atomicAdd(&my[r.z], 1u);
        atomicAdd(&my[r.w], 1u);
    }
    int e = nvec * 4 + i;
    if (e < E) atomicAdd(&my[row[e]], 1u);
}

__global__ __launch_bounds__(256) void node_kernel(const unsigned int* __restrict__ counts,
                                                   const int* __restrict__ atom_types,
                                                   float* __restrict__ sarr,
                                                   float* __restrict__ viol,
                                                   int N, float inv_n) {
    int stride = gridDim.x * 256;
    float local = 0.0f;
    for (int r = blockIdx.x * 256 + threadIdx.x; r < N; r += stride) {
        unsigned int c = 0;
        #pragma unroll
        for (int k = 0; k < NREP; ++k) c += counts[(size_t)k * (size_t)N + r];
        int t = atom_types[r];
        float maxv = (t >= 0 && t < 11) ? c_maxv[t] : 4.0f;
        float v = fmaxf((float)c - maxv, 0.0f);
        sarr[r] = 1.0f - 0.1f * v;
        local += v * v;
    }
    for (int off = 32; off > 0; off >>= 1)
        local += __shfl_down(local, off, 64);
    __shared__ float sdata[4];
    if ((threadIdx.x & 63) == 0) sdata[threadIdx.x >> 6] = local;
    __syncthreads();
    if (threadIdx.x == 0)
        atomicAdd(viol, (sdata[0] + sdata[1] + sdata[2] + sdata[3]) * inv_n);
}

__global__ __launch_bounds__(256) void scale_kernel(const float4* __restrict__ h,
                                                    const float* __restrict__ sarr,
                                                    float4* __restrict__ out,
                                                    int total, int cpr_shift) {
    int stride = gridDim.x * 256;
    for (int idx = blockIdx.x * 256 + threadIdx.x; idx < total; idx += stride) {
        float s = sarr[idx >> cpr_shift];
        float4 hv = h[idx];
        hv.x *= s; hv.y *= s; hv.z *= s; hv.w *= s;
        out[idx] = hv;
    }
}

extern "C" void kernel_launch(void* const* d_in, const int* in_sizes, int n_in,
                              void* d_out, int out_size, void* d_ws, size_t ws_size,
                              hipStream_t stream) {
    const float* h          = (const float*)d_in[0];
    const int*   edge       = (const int*)d_in[1];   // row = edge[0..E-1]
    const int*   atom_types = (const int*)d_in[3];

    int N = in_sizes[3];
    int D = in_sizes[0] / N;        // 128
    int E = in_sizes[1] / 2;        // 16M

    float* out  = (float*)d_out;
    float* viol = out + (size_t)N * (size_t)D;

    int B = (N + RANGE - 1) >> RSHIFT;   // 245 buckets for N=500000

    // per-bucket capacity: mean + 16 sigma + 1024, rounded to 64 (overflow P ~ e^-128)
    double mean = (double)E * (double)RANGE / (double)N;
    int CAP = (int)(mean + 16.0 * sqrt(mean > 1.0 ? mean : 1.0) + 1024.0);
    CAP = (CAP + 63) & ~63;

    size_t seg_bytes = ((size_t)B * (size_t)CAP * 2 + 255) & ~(size_t)255;
    size_t ctl_bytes = (size_t)BPAD * 4 + 64;   // gcursor + vz + done
    size_t need_new  = seg_bytes + ctl_bytes;

    if (B <= BPAD && D == 128 && ws_size >= need_new) {
        // ws layout: [seg u16 (B*CAP)][gcursor BPAD u32][vz f32][done u32]
        unsigned short* seg     = (unsigned short*)d_ws;
        unsigned int*   gcursor = (unsigned int*)((char*)d_ws + seg_bytes);
        float*          vz      = (float*)((char*)d_ws + seg_bytes + (size_t)BPAD * 4);
        unsigned int*   done    = (unsigned int*)(vz + 1);

        (void)hipMemsetAsync(gcursor, 0, ctl_bytes, stream);  // cursors+vz+done

        int sblocks = (E + EPB - 1) / EPB;
        scatter_kernel<<<sblocks, SBLK, 0, stream>>>(edge, seg, gcursor, E, CAP);
        fused_kernel<<<B, 1024, 0, stream>>>(seg, gcursor, atom_types,
                                             h, out, viol, vz, done, N, CAP,
                                             1.0f / (float)N, B);
    } else {
        // fallback: previous verified path
        unsigned int* counts = (unsigned int*)d_ws;
        float* sarr = (float*)((char*)d_ws + (size_t)NREP * N * 4);
        (void)hipMemsetAsync(counts, 0, (size_t)NREP * N * sizeof(unsigned int), stream);
        (void)hipMemsetAsync(viol, 0, sizeof(float), stream);
        int nvec = E / 4;
        int cblocks = (nvec + 255) / 256;
        count_kernel<<<cblocks, 256, 0, stream>>>(edge, counts, nvec, E, N);
        node_kernel<<<512, 256, 0, stream>>>(counts, atom_types, sarr, viol, N,
                                             1.0f / (float)N);
        int cpr = D / 4;
        int cpr_shift = 0; while ((1 << cpr_shift) < cpr) ++cpr_shift;
        int total = N * cpr;
        scale_kernel<<<8192, 256, 0, stream>>>((const float4*)h, sarr,
                                               (float4*)out, total, cpr_shift);
    }
}